// Round 16
// baseline (416.215 us; speedup 1.0000x reference)
//
#include <hip/hip_runtime.h>
#include <hip/hip_bf16.h>
#include <stdint.h>

// LocalExperts grouped FFN: out[e] = relu(x[e] @ wi[e]) @ wo[e]
// E=8, M=W*C=8192 rows/expert, D=512, F=2048. fp32 in/out.
// Round 16 = round 10 (validated 351us; r11-r15 epilogue/L3 experiments all
// reverted) + NON-TEMPORAL epilogue stores (__builtin_nontemporal_store) for
// the h (bf16) and out (fp32) streams. Mechanism under test: L2 write-
// allocate pollution — the 262 MB h-stream evicts A/B panels and ties store
// retirement to dirty-eviction bandwidth, which the per-K-tile VM8 then
// serializes on. nt keeps streaming writes out of the L2 allocation path.
// [VALIDATED round-4/10 main loop — do not edit sync]

#define E_N 8
#define W_N 8
#define C_N 1024
#define D_N 512
#define F_N 2048
#define ME  (W_N * C_N)   // 8192 rows per expert

typedef __attribute__((ext_vector_type(4))) float f32x4;
typedef __attribute__((ext_vector_type(8))) short s16x8;

#define BAR()  __builtin_amdgcn_s_barrier()
#define SBAR() __builtin_amdgcn_sched_barrier(0)
#define LGKM0() do { asm volatile("s_waitcnt lgkmcnt(0)" ::: "memory"); SBAR(); } while (0)
#define VM8()   do { asm volatile("s_waitcnt vmcnt(8)"   ::: "memory"); SBAR(); } while (0)
#define VM0()   do { asm volatile("s_waitcnt vmcnt(0)"   ::: "memory"); SBAR(); } while (0)

__device__ __forceinline__ unsigned short f2bf(float f) {
  union { float f; unsigned int u; } v; v.f = f;
  unsigned int u = v.u + 0x7fffu + ((v.u >> 16) & 1u);  // RNE
  return (unsigned short)(u >> 16);
}

__device__ __forceinline__ void gload_lds16(void* lds, const void* g) {
  __builtin_amdgcn_global_load_lds(
      (const __attribute__((address_space(1))) unsigned int*)g,
      (__attribute__((address_space(3))) unsigned int*)lds, 16, 0, 0);
}

// ---- fused prep: transpose+cvt wi, transpose+cvt wo, cvt x ----
__device__ __forceinline__ void transpose_tile(
    const float* __restrict__ in, unsigned short* __restrict__ out,
    int R, int Ccols, int bx, int by, int bz) {
  __shared__ unsigned short tile[64][65];
  const float* ip = in + (size_t)bz * R * Ccols;
  unsigned short* op = out + (size_t)bz * R * Ccols;
  const int c0 = bx * 64, r0 = by * 64;
  const int t = threadIdx.x;
  const int cl = (t & 15) * 4, rw = t >> 4;
#pragma unroll
  for (int i = 0; i < 4; ++i) {
    int row = rw + i * 16;
    float4 v = *(const float4*)&ip[(size_t)(r0 + row) * Ccols + c0 + cl];
    tile[row][cl + 0] = f2bf(v.x);
    tile[row][cl + 1] = f2bf(v.y);
    tile[row][cl + 2] = f2bf(v.z);
    tile[row][cl + 3] = f2bf(v.w);
  }
  __syncthreads();
#pragma unroll
  for (int i = 0; i < 4; ++i) {
    int oc = rw + i * 16;
    ushort4 o;
    o.x = tile[cl + 0][oc];
    o.y = tile[cl + 1][oc];
    o.z = tile[cl + 2][oc];
    o.w = tile[cl + 3][oc];
    *(ushort4*)&op[(size_t)(c0 + oc) * R + r0 + cl] = o;
  }
}

__global__ __launch_bounds__(256)
void prep_fused(const float* __restrict__ x, const float* __restrict__ wi,
                const float* __restrict__ wo, unsigned short* __restrict__ xb,
                unsigned short* __restrict__ wiT, unsigned short* __restrict__ woT) {
  const int id = blockIdx.x;
  if (id < 2048) {
    transpose_tile(wi, wiT, D_N, F_N, id % 32, (id / 32) % 8, id / 256);
  } else if (id < 4096) {
    const int v = id - 2048;
    transpose_tile(wo, woT, F_N, D_N, v % 8, (v / 8) % 32, v / 256);
  } else {
    const int v = id - 4096;
    const size_t n = (size_t)E_N * ME * D_N;
    size_t idx = ((size_t)v * 256 + threadIdx.x) * 8;
    const size_t stride = (size_t)2048 * 256 * 8;
    for (; idx < n; idx += stride) {
      float4 a = *(const float4*)&x[idx];
      float4 b = *(const float4*)&x[idx + 4];
      union { s16x8 v8; unsigned short u[8]; } p;
      p.u[0] = f2bf(a.x); p.u[1] = f2bf(a.y); p.u[2] = f2bf(a.z); p.u[3] = f2bf(a.w);
      p.u[4] = f2bf(b.x); p.u[5] = f2bf(b.y); p.u[6] = f2bf(b.z); p.u[7] = f2bf(b.w);
      *(s16x8*)&xb[idx] = p.v8;
    }
  }
}

// Persistent C[M,N] = A[M,K] @ Bt[N,K]^T, bf16 in, fp32 acc. Grid = 256.
// Block b: e = b&7 (expert<->XCD), bi = b>>3: n0 = (bi%nT)*256 fixed,
// ms = bi/nT, sweeps TS=nT row-tiles. Per tile: NK = K/64 K-tiles, 2/iter,
// 8 phases. LDS 128 KiB: [buf2][A/B][half2][128][64] bf16, XOR-swizzle
// g_phys = g_log ^ (row&7). Cross-tile prefetch; vmcnt(8) once per K-tile.
// [VALIDATED round-4 structure — do not edit sync]
template<bool RELU_BF16_OUT>
__global__ __launch_bounds__(512, 2)
void gemm256p(const unsigned short* __restrict__ Abase,
              const unsigned short* __restrict__ Btbase,
              void* __restrict__ Cv, int N, int K, int nT,
              size_t aStrideE, size_t bStrideE, size_t cStrideE) {
  extern __shared__ unsigned short lds[];
  unsigned char* ldsb = (unsigned char*)lds;
  const int blk = blockIdx.x;
  const int e  = blk & 7;
  const int bi = blk >> 3;
  const int TS = nT;                       // row-tiles per block
  const int n0 = (bi % nT) * 256;
  const int ms = bi / nT;
  const int tid  = threadIdx.x;
  const int lane = tid & 63;
  const int wave = tid >> 6;
  const int wm = wave >> 2;   // 0..1 : row-half of C
  const int wn = wave & 3;    // 0..3 : 64-col slice of C
  const unsigned short* A  = Abase  + (size_t)e * aStrideE;
  const unsigned short* Bt = Btbase + (size_t)e * bStrideE;

  const int NK = K >> 6;                 // K-tiles per output tile (even, pow2)
  const int kshift = __builtin_ctz(NK);
  const int total = TS * NK;             // global K-tile stream length

  // ---- per-thread ds_read addressing (bytes) ----
  const int rl = lane & 15;
  const int gb = lane >> 4;
  const int g16_0 = ((0 * 4 + gb) ^ (rl & 7)) * 16;
  const int g16_1 = ((1 * 4 + gb) ^ (rl & 7)) * 16;
  const int aBase0 = wm * 16384 + rl * 128;
  const int bBase0 = 32768 + (wn >> 1) * 16384 + ((wn & 1) * 64 + rl) * 128;

  // ---- per-thread stage addressing (pre-swizzled global source) ----
  int rA0[2], rB0[2];
#pragma unroll
  for (int o = 0; o < 2; ++o) {
    int G = o * 512 + tid;            // physical LDS granule within half-tile
    int r = G >> 3;                   // row 0..127
    int gl = (G & 7) ^ (r & 7);       // logical granule (inverse swizzle)
    rA0[o] = r * K + gl * 8;          // relative to tile's m0
    rB0[o] = (n0 + r) * K + gl * 8;   // n0 fixed for the block
  }
  auto stageA = [&](int g, int h) {
    const int ktl = g & (NK - 1);
    const int buf = g & 1;
    const int m0t = (ms * TS + (g >> kshift)) * 256;
    const unsigned short* An = A + (size_t)m0t * K;
#pragma unroll
    for (int o = 0; o < 2; ++o)
      gload_lds16(ldsb + buf * 65536 + h * 16384 + o * 8192 + wave * 1024,
                  An + rA0[o] + h * 128 * K + ktl * 64);
  };
  auto stageB = [&](int g, int h) {
    const int ktl = g & (NK - 1);
    const int buf = g & 1;
#pragma unroll
    for (int o = 0; o < 2; ++o)
      gload_lds16(ldsb + buf * 65536 + 32768 + h * 16384 + o * 8192 + wave * 1024,
                  Bt + rB0[o] + h * 128 * K + ktl * 64);
  };

  f32x4 acc[8][4] = {};

  // ---- one K-tile: 4 phases, 16 MFMA each; stages K-tile gN (2 ahead) ----
  auto run_ktile = [&](int buf, int gN, bool more, bool needDrain) {
    const int bufOff = buf * 65536;
    s16x8 afr[4][2], b01[2][2], b23[2][2];
    // -- Pa --
#pragma unroll
    for (int mi = 0; mi < 4; ++mi) {
      afr[mi][0] = *(const s16x8*)(ldsb + bufOff + aBase0 + mi * 2048 + g16_0);
      afr[mi][1] = *(const s16x8*)(ldsb + bufOff + aBase0 + mi * 2048 + g16_1);
    }
#pragma unroll
    for (int ni = 0; ni < 2; ++ni) {
      b01[ni][0] = *(const s16x8*)(ldsb + bufOff + bBase0 + ni * 2048 + g16_0);
      b01[ni][1] = *(const s16x8*)(ldsb + bufOff + bBase0 + ni * 2048 + g16_1);
    }
    BAR(); LGKM0();
    __builtin_amdgcn_s_setprio(1);
#pragma unroll
    for (int mi = 0; mi < 4; ++mi)
#pragma unroll
      for (int ni = 0; ni < 2; ++ni) {
        acc[mi][ni] = __builtin_amdgcn_mfma_f32_16x16x32_bf16(afr[mi][0], b01[ni][0], acc[mi][ni], 0, 0, 0);
        acc[mi][ni] = __builtin_amdgcn_mfma_f32_16x16x32_bf16(afr[mi][1], b01[ni][1], acc[mi][ni], 0, 0, 0);
      }
    __builtin_amdgcn_s_setprio(0);
    BAR();
    // -- Pb --
#pragma unroll
    for (int ni = 0; ni < 2; ++ni) {
      b23[ni][0] = *(const s16x8*)(ldsb + bufOff + bBase0 + (2 + ni) * 2048 + g16_0);
      b23[ni][1] = *(const s16x8*)(ldsb + bufOff + bBase0 + (2 + ni) * 2048 + g16_1);
    }
    BAR(); LGKM0();
    __builtin_amdgcn_s_setprio(1);
#pragma unroll
    for (int mi = 0; mi < 4; ++mi)
#pragma unroll
      for (int ni = 0; ni < 2; ++ni) {
        acc[mi][2 + ni] = __builtin_amdgcn_mfma_f32_16x16x32_bf16(afr[mi][0], b23[ni][0], acc[mi][2 + ni], 0, 0, 0);
        acc[mi][2 + ni] = __builtin_amdgcn_mfma_f32_16x16x32_bf16(afr[mi][1], b23[ni][1], acc[mi][2 + ni], 0, 0, 0);
      }
    __builtin_amdgcn_s_setprio(0);
    BAR();
    // -- Pc --
#pragma unroll
    for (int mi = 0; mi < 4; ++mi) {
      afr[mi][0] = *(const s16x8*)(ldsb + bufOff + aBase0 + (4 + mi) * 2048 + g16_0);
      afr[mi][1] = *(const s16x8*)(ldsb + bufOff + aBase0 + (4 + mi) * 2048 + g16_1);
    }
    if (more) { stageB(gN, 0); stageB(gN, 1); }
    BAR(); LGKM0();
    __builtin_amdgcn_s_setprio(1);
#pragma unroll
    for (int mi = 0; mi < 4; ++mi)
#pragma unroll
      for (int ni = 0; ni < 2; ++ni) {
        acc[4 + mi][2 + ni] = __builtin_amdgcn_mfma_f32_16x16x32_bf16(afr[mi][0], b23[ni][0], acc[4 + mi][2 + ni], 0, 0, 0);
        acc[4 + mi][2 + ni] = __builtin_amdgcn_mfma_f32_16x16x32_bf16(afr[mi][1], b23[ni][1], acc[4 + mi][2 + ni], 0, 0, 0);
      }
    __builtin_amdgcn_s_setprio(0);
    BAR();
    // -- Pd --
    if (more) { stageA(gN, 0); stageA(gN, 1); }
    BAR();
    __builtin_amdgcn_s_setprio(1);
#pragma unroll
    for (int mi = 0; mi < 4; ++mi)
#pragma unroll
      for (int ni = 0; ni < 2; ++ni) {
        acc[4 + mi][ni] = __builtin_amdgcn_mfma_f32_16x16x32_bf16(afr[mi][0], b01[ni][0], acc[4 + mi][ni], 0, 0, 0);
        acc[4 + mi][ni] = __builtin_amdgcn_mfma_f32_16x16x32_bf16(afr[mi][1], b01[ni][1], acc[4 + mi][ni], 0, 0, 0);
      }
    __builtin_amdgcn_s_setprio(0);
    if (more) { VM8(); } else if (needDrain) { VM0(); }
    BAR();
  };

  // ---- prologue: stage global K-tiles 0 and 1 (both in tile 0) ----
  stageB(0, 0); stageB(0, 1); stageA(0, 0); stageA(0, 1);
  stageB(1, 0); stageB(1, 1); stageA(1, 0); stageA(1, 1);
  VM8();
  BAR();

  const int rq = (lane >> 4) * 4;
  const int cq = lane & 15;

  for (int g = 0; g < total; g += 2) {
    run_ktile(0, g + 2, (g + 2 < total), true);
    run_ktile(1, g + 3, (g + 3 < total), false);
    if (((g + 2) & (NK - 1)) == 0) {
      // ---- epilogue for finished tile (C/D: col=lane&15, row=(lane>>4)*4+reg
      //      — m89/m91); NON-TEMPORAL stores (streaming, no L2 allocate) ----
      const int m0 = (ms * TS + (g >> kshift)) * 256;
      if (RELU_BF16_OUT) {
        unsigned short* Cb = (unsigned short*)Cv + (size_t)e * cStrideE;
#pragma unroll
        for (int mi = 0; mi < 8; ++mi)
#pragma unroll
          for (int ni = 0; ni < 4; ++ni) {
            int row0 = m0 + wm * 128 + mi * 16 + rq;
            int col  = n0 + wn * 64 + ni * 16 + cq;
#pragma unroll
            for (int r = 0; r < 4; ++r) {
              float v = acc[mi][ni][r];
              v = v > 0.f ? v : 0.f;
              __builtin_nontemporal_store(f2bf(v), &Cb[(size_t)(row0 + r) * N + col]);
            }
          }
      } else {
        float* Cf = (float*)Cv + (size_t)e * cStrideE;
#pragma unroll
        for (int mi = 0; mi < 8; ++mi)
#pragma unroll
          for (int ni = 0; ni < 4; ++ni) {
            int row0 = m0 + wm * 128 + mi * 16 + rq;
            int col  = n0 + wn * 64 + ni * 16 + cq;
#pragma unroll
            for (int r = 0; r < 4; ++r)
              __builtin_nontemporal_store(acc[mi][ni][r], &Cf[(size_t)(row0 + r) * N + col]);
          }
      }
#pragma unroll
      for (int mi = 0; mi < 8; ++mi)
#pragma unroll
        for (int ni = 0; ni < 4; ++ni)
          acc[mi][ni] = (f32x4){0.f, 0.f, 0.f, 0.f};
    }
  }
}

// Zero-workspace fp32 fallback (correct, slow). One block per token row.
__global__ __launch_bounds__(256)
void fused_naive(const float* __restrict__ x, const float* __restrict__ wi,
                 const float* __restrict__ wo, float* __restrict__ out) {
  __shared__ float xs[D_N];
  __shared__ float hs[F_N];
  const size_t row = blockIdx.x;
  const int e = (int)(row / (W_N * C_N));
  const float* xr = x + row * D_N;
  const float* wie = wi + (size_t)e * D_N * F_N;
  const float* woe = wo + (size_t)e * F_N * D_N;
  const int t = threadIdx.x;
  for (int d = t; d < D_N; d += 256) xs[d] = xr[d];
  __syncthreads();
  for (int f = t; f < F_N; f += 256) {
    float a = 0.f;
    for (int d = 0; d < D_N; ++d) a += xs[d] * wie[(size_t)d * F_N + f];
    hs[f] = a > 0.f ? a : 0.f;
  }
  __syncthreads();
  float* orow = out + row * D_N;
  for (int d = t; d < D_N; d += 256) {
    float a = 0.f;
    for (int f = 0; f < F_N; ++f) a += hs[f] * woe[(size_t)f * D_N + d];
    orow[d] = a;
  }
}

extern "C" void kernel_launch(void* const* d_in, const int* in_sizes, int n_in,
                              void* d_out, int out_size, void* d_ws, size_t ws_size,
                              hipStream_t stream) {
  const float* x  = (const float*)d_in[0];
  // d_in[1] = experts_capacity_usage: unused by the reference math
  const float* wi = (const float*)d_in[2];
  const float* wo = (const float*)d_in[3];
  float* out = (float*)d_out;

  const size_t WT   = (size_t)E_N * D_N * F_N;       // elems per weight tensor
  unsigned short* wiT = (unsigned short*)d_ws;       // [E][F][D] bf16
  unsigned short* woT = wiT + WT;                    // [E][D][F] bf16
  unsigned short* P   = woT + WT;
  const size_t baseB = 2 * WT * 2;                   // 32 MiB
  const size_t XB_B  = (size_t)E_N * ME * D_N * 2;   // x as bf16
  const size_t HF_B  = (size_t)E_N * ME * F_N * 2;   // full h

  const dim3 blk(256);
  if (ws_size >= baseB + XB_B + HF_B) {
    hipFuncSetAttribute(reinterpret_cast<const void*>(gemm256p<true>),
                        hipFuncAttributeMaxDynamicSharedMemorySize, 131072);
    hipFuncSetAttribute(reinterpret_cast<const void*>(gemm256p<false>),
                        hipFuncAttributeMaxDynamicSharedMemorySize, 131072);
    unsigned short* xb = P;
    unsigned short* h  = P + XB_B / 2;
    prep_fused<<<dim3(6144), blk, 0, stream>>>(x, wi, wo, xb, wiT, woT);
    // GEMM1: per expert M=8192,N=2048,K=512 -> nT=8, TS=8 row-tiles/block
    gemm256p<true><<<dim3(256), dim3(512), 131072, stream>>>(
        xb, wiT, h, F_N, D_N, F_N / 256,
        (size_t)ME * D_N, (size_t)F_N * D_N, (size_t)ME * F_N);
    // GEMM2: per expert M=8192,N=512,K=2048 -> nT=2, TS=2 row-tiles/block
    gemm256p<false><<<dim3(256), dim3(512), 131072, stream>>>(
        h, woT, out, D_N, F_N, D_N / 256,
        (size_t)ME * F_N, (size_t)D_N * F_N, (size_t)ME * D_N);
  } else {
    fused_naive<<<dim3(E_N * W_N * C_N), blk, 0, stream>>>(x, wi, wo, out);
  }
}

// Round 17
// 337.149 us; speedup vs baseline: 1.2345x; 1.2345x over previous
//
#include <hip/hip_runtime.h>
#include <hip/hip_bf16.h>
#include <stdint.h>

// LocalExperts grouped FFN: out[e] = relu(x[e] @ wi[e]) @ wo[e]
// E=8, M=W*C=8192 rows/expert, D=512, F=2048. fp32 in/out.
// Round 17 = round 10 (validated) + STORE-DRAIN FIX. Diagnosis (r16):
// vmcnt counts stores, retirement is in-order -> each epilogue's 128
// scalar stores are force-drained by the next K-tile's VM8 (~11 us x8 on
// GEMM1). Fix: (a) wave-local slab repack (r12 machinery) -> 16 (bf16) /
// 32 (fp32) dwordx4 full-line NT stores per thread (no L2 pollution, no
// RMW amplification -- r16's 2.2x was scalar-nt partial lines);
// (b) first post-epilogue wait = VM24/VM40 = stores+8, which retires
// exactly the previous K-tile's prefetch and leaves stores draining under
// MFMA. All other waits byte-identical to the validated r4/r10 ledger.

#define E_N 8
#define W_N 8
#define C_N 1024
#define D_N 512
#define F_N 2048
#define ME  (W_N * C_N)   // 8192 rows per expert

typedef __attribute__((ext_vector_type(4))) float f32x4;
typedef __attribute__((ext_vector_type(4))) unsigned int u32x4;
typedef __attribute__((ext_vector_type(8))) short s16x8;

#define BAR()  __builtin_amdgcn_s_barrier()
#define SBAR() __builtin_amdgcn_sched_barrier(0)
#define CFENCE() do { asm volatile("" ::: "memory"); SBAR(); } while (0)
#define LGKM0() do { asm volatile("s_waitcnt lgkmcnt(0)" ::: "memory"); SBAR(); } while (0)
#define VM8()   do { asm volatile("s_waitcnt vmcnt(8)"   ::: "memory"); SBAR(); } while (0)
#define VM24()  do { asm volatile("s_waitcnt vmcnt(24)"  ::: "memory"); SBAR(); } while (0)
#define VM40()  do { asm volatile("s_waitcnt vmcnt(40)"  ::: "memory"); SBAR(); } while (0)
#define VM0()   do { asm volatile("s_waitcnt vmcnt(0)"   ::: "memory"); SBAR(); } while (0)

__device__ __forceinline__ unsigned short f2bf(float f) {
  union { float f; unsigned int u; } v; v.f = f;
  unsigned int u = v.u + 0x7fffu + ((v.u >> 16) & 1u);  // RNE
  return (unsigned short)(u >> 16);
}

__device__ __forceinline__ void gload_lds16(void* lds, const void* g) {
  __builtin_amdgcn_global_load_lds(
      (const __attribute__((address_space(1))) unsigned int*)g,
      (__attribute__((address_space(3))) unsigned int*)lds, 16, 0, 0);
}

// ---- fused prep: transpose+cvt wi, transpose+cvt wo, cvt x ----
__device__ __forceinline__ void transpose_tile(
    const float* __restrict__ in, unsigned short* __restrict__ out,
    int R, int Ccols, int bx, int by, int bz) {
  __shared__ unsigned short tile[64][65];
  const float* ip = in + (size_t)bz * R * Ccols;
  unsigned short* op = out + (size_t)bz * R * Ccols;
  const int c0 = bx * 64, r0 = by * 64;
  const int t = threadIdx.x;
  const int cl = (t & 15) * 4, rw = t >> 4;
#pragma unroll
  for (int i = 0; i < 4; ++i) {
    int row = rw + i * 16;
    float4 v = *(const float4*)&ip[(size_t)(r0 + row) * Ccols + c0 + cl];
    tile[row][cl + 0] = f2bf(v.x);
    tile[row][cl + 1] = f2bf(v.y);
    tile[row][cl + 2] = f2bf(v.z);
    tile[row][cl + 3] = f2bf(v.w);
  }
  __syncthreads();
#pragma unroll
  for (int i = 0; i < 4; ++i) {
    int oc = rw + i * 16;
    ushort4 o;
    o.x = tile[cl + 0][oc];
    o.y = tile[cl + 1][oc];
    o.z = tile[cl + 2][oc];
    o.w = tile[cl + 3][oc];
    *(ushort4*)&op[(size_t)(c0 + oc) * R + r0 + cl] = o;
  }
}

__global__ __launch_bounds__(256)
void prep_fused(const float* __restrict__ x, const float* __restrict__ wi,
                const float* __restrict__ wo, unsigned short* __restrict__ xb,
                unsigned short* __restrict__ wiT, unsigned short* __restrict__ woT) {
  const int id = blockIdx.x;
  if (id < 2048) {
    transpose_tile(wi, wiT, D_N, F_N, id % 32, (id / 32) % 8, id / 256);
  } else if (id < 4096) {
    const int v = id - 2048;
    transpose_tile(wo, woT, F_N, D_N, v % 8, (v / 8) % 32, v / 256);
  } else {
    const int v = id - 4096;
    const size_t n = (size_t)E_N * ME * D_N;
    size_t idx = ((size_t)v * 256 + threadIdx.x) * 8;
    const size_t stride = (size_t)2048 * 256 * 8;
    for (; idx < n; idx += stride) {
      float4 a = *(const float4*)&x[idx];
      float4 b = *(const float4*)&x[idx + 4];
      union { s16x8 v8; unsigned short u[8]; } p;
      p.u[0] = f2bf(a.x); p.u[1] = f2bf(a.y); p.u[2] = f2bf(a.z); p.u[3] = f2bf(a.w);
      p.u[4] = f2bf(b.x); p.u[5] = f2bf(b.y); p.u[6] = f2bf(b.z); p.u[7] = f2bf(b.w);
      *(s16x8*)&xb[idx] = p.v8;
    }
  }
}

// Persistent C[M,N] = A[M,K] @ Bt[N,K]^T, bf16 in, fp32 acc. Grid = 256.
// [VALIDATED r4/r10 main loop]. New: epilogue = wave-local slab repack +
// full-line NT dwordx4 stores; first post-epilogue end-wait VM24/VM40
// (= nStores+8: retires exactly the previous K-tile's 8 prefetch loads,
// leaves the epilogue stores draining under the next K-tile's MFMA).
template<bool RELU_BF16_OUT>
__global__ __launch_bounds__(512, 2)
void gemm256p(const unsigned short* __restrict__ Abase,
              const unsigned short* __restrict__ Btbase,
              void* __restrict__ Cv, int N, int K, int nT,
              size_t aStrideE, size_t bStrideE, size_t cStrideE) {
  extern __shared__ unsigned short lds[];
  unsigned char* ldsb = (unsigned char*)lds;
  const int blk = blockIdx.x;
  const int e  = blk & 7;
  const int bi = blk >> 3;
  const int TS = nT;                       // row-tiles per block
  const int n0 = (bi % nT) * 256;
  const int ms = bi / nT;
  const int tid  = threadIdx.x;
  const int lane = tid & 63;
  const int wave = tid >> 6;
  const int wm = wave >> 2;   // 0..1 : row-half of C
  const int wn = wave & 3;    // 0..3 : 64-col slice of C
  const unsigned short* A  = Abase  + (size_t)e * aStrideE;
  const unsigned short* Bt = Btbase + (size_t)e * bStrideE;

  const int NK = K >> 6;                 // K-tiles per output tile (even, pow2)
  const int kshift = __builtin_ctz(NK);
  const int total = TS * NK;             // global K-tile stream length

  // ---- per-thread ds_read addressing (bytes) ----
  const int rl = lane & 15;
  const int gb = lane >> 4;
  const int g16_0 = ((0 * 4 + gb) ^ (rl & 7)) * 16;
  const int g16_1 = ((1 * 4 + gb) ^ (rl & 7)) * 16;
  const int aBase0 = wm * 16384 + rl * 128;
  const int bBase0 = 32768 + (wn >> 1) * 16384 + ((wn & 1) * 64 + rl) * 128;

  // ---- per-thread stage addressing (pre-swizzled global source) ----
  int rA0[2], rB0[2];
#pragma unroll
  for (int o = 0; o < 2; ++o) {
    int G = o * 512 + tid;            // physical LDS granule within half-tile
    int r = G >> 3;                   // row 0..127
    int gl = (G & 7) ^ (r & 7);       // logical granule (inverse swizzle)
    rA0[o] = r * K + gl * 8;          // relative to tile's m0
    rB0[o] = (n0 + r) * K + gl * 8;   // n0 fixed for the block
  }
  auto stageA = [&](int g, int h) {
    const int ktl = g & (NK - 1);
    const int buf = g & 1;
    const int m0t = (ms * TS + (g >> kshift)) * 256;
    const unsigned short* An = A + (size_t)m0t * K;
#pragma unroll
    for (int o = 0; o < 2; ++o)
      gload_lds16(ldsb + buf * 65536 + h * 16384 + o * 8192 + wave * 1024,
                  An + rA0[o] + h * 128 * K + ktl * 64);
  };
  auto stageB = [&](int g, int h) {
    const int ktl = g & (NK - 1);
    const int buf = g & 1;
#pragma unroll
    for (int o = 0; o < 2; ++o)
      gload_lds16(ldsb + buf * 65536 + 32768 + h * 16384 + o * 8192 + wave * 1024,
                  Bt + rB0[o] + h * 128 * K + ktl * 64);
  };

  f32x4 acc[8][4] = {};

  // ---- one K-tile: 4 phases, 16 MFMA each; stages K-tile gN (2 ahead).
  //      bigWait: first K-tile after an epilogue -> VM24/VM40 (see header) ----
  auto run_ktile = [&](int buf, int gN, bool more, bool needDrain, bool bigWait) {
    const int bufOff = buf * 65536;
    s16x8 afr[4][2], b01[2][2], b23[2][2];
    // -- Pa --
#pragma unroll
    for (int mi = 0; mi < 4; ++mi) {
      afr[mi][0] = *(const s16x8*)(ldsb + bufOff + aBase0 + mi * 2048 + g16_0);
      afr[mi][1] = *(const s16x8*)(ldsb + bufOff + aBase0 + mi * 2048 + g16_1);
    }
#pragma unroll
    for (int ni = 0; ni < 2; ++ni) {
      b01[ni][0] = *(const s16x8*)(ldsb + bufOff + bBase0 + ni * 2048 + g16_0);
      b01[ni][1] = *(const s16x8*)(ldsb + bufOff + bBase0 + ni * 2048 + g16_1);
    }
    BAR(); LGKM0();
    __builtin_amdgcn_s_setprio(1);
#pragma unroll
    for (int mi = 0; mi < 4; ++mi)
#pragma unroll
      for (int ni = 0; ni < 2; ++ni) {
        acc[mi][ni] = __builtin_amdgcn_mfma_f32_16x16x32_bf16(afr[mi][0], b01[ni][0], acc[mi][ni], 0, 0, 0);
        acc[mi][ni] = __builtin_amdgcn_mfma_f32_16x16x32_bf16(afr[mi][1], b01[ni][1], acc[mi][ni], 0, 0, 0);
      }
    __builtin_amdgcn_s_setprio(0);
    BAR();
    // -- Pb --
#pragma unroll
    for (int ni = 0; ni < 2; ++ni) {
      b23[ni][0] = *(const s16x8*)(ldsb + bufOff + bBase0 + (2 + ni) * 2048 + g16_0);
      b23[ni][1] = *(const s16x8*)(ldsb + bufOff + bBase0 + (2 + ni) * 2048 + g16_1);
    }
    BAR(); LGKM0();
    __builtin_amdgcn_s_setprio(1);
#pragma unroll
    for (int mi = 0; mi < 4; ++mi)
#pragma unroll
      for (int ni = 0; ni < 2; ++ni) {
        acc[mi][2 + ni] = __builtin_amdgcn_mfma_f32_16x16x32_bf16(afr[mi][0], b23[ni][0], acc[mi][2 + ni], 0, 0, 0);
        acc[mi][2 + ni] = __builtin_amdgcn_mfma_f32_16x16x32_bf16(afr[mi][1], b23[ni][1], acc[mi][2 + ni], 0, 0, 0);
      }
    __builtin_amdgcn_s_setprio(0);
    BAR();
    // -- Pc --
#pragma unroll
    for (int mi = 0; mi < 4; ++mi) {
      afr[mi][0] = *(const s16x8*)(ldsb + bufOff + aBase0 + (4 + mi) * 2048 + g16_0);
      afr[mi][1] = *(const s16x8*)(ldsb + bufOff + aBase0 + (4 + mi) * 2048 + g16_1);
    }
    if (more) { stageB(gN, 0); stageB(gN, 1); }
    BAR(); LGKM0();
    __builtin_amdgcn_s_setprio(1);
#pragma unroll
    for (int mi = 0; mi < 4; ++mi)
#pragma unroll
      for (int ni = 0; ni < 2; ++ni) {
        acc[4 + mi][2 + ni] = __builtin_amdgcn_mfma_f32_16x16x32_bf16(afr[mi][0], b23[ni][0], acc[4 + mi][2 + ni], 0, 0, 0);
        acc[4 + mi][2 + ni] = __builtin_amdgcn_mfma_f32_16x16x32_bf16(afr[mi][1], b23[ni][1], acc[4 + mi][2 + ni], 0, 0, 0);
      }
    __builtin_amdgcn_s_setprio(0);
    BAR();
    // -- Pd --
    if (more) { stageA(gN, 0); stageA(gN, 1); }
    BAR();
    __builtin_amdgcn_s_setprio(1);
#pragma unroll
    for (int mi = 0; mi < 4; ++mi)
#pragma unroll
      for (int ni = 0; ni < 2; ++ni) {
        acc[4 + mi][ni] = __builtin_amdgcn_mfma_f32_16x16x32_bf16(afr[mi][0], b01[ni][0], acc[4 + mi][ni], 0, 0, 0);
        acc[4 + mi][ni] = __builtin_amdgcn_mfma_f32_16x16x32_bf16(afr[mi][1], b01[ni][1], acc[4 + mi][ni], 0, 0, 0);
      }
    __builtin_amdgcn_s_setprio(0);
    if (more) {
      if (bigWait) { if (RELU_BF16_OUT) { VM24(); } else { VM40(); } }
      else         { VM8(); }
    } else if (needDrain) { VM0(); }
    BAR();
  };

  // ---- prologue: stage global K-tiles 0 and 1 (both in tile 0) ----
  stageB(0, 0); stageB(0, 1); stageA(0, 0); stageA(0, 1);
  stageB(1, 0); stageB(1, 1); stageA(1, 0); stageA(1, 1);
  VM8();
  BAR();

  const int rq = (lane >> 4) * 4;
  const int cq = lane & 15;
  // wave-local repack slabs at ldsb+131072 (2112 B/wave, disjoint from staging)
  unsigned short* slabW = (unsigned short*)(ldsb + 131072) + wave * 1056;
  float*          slabF = (float*)(ldsb + 131072) + wave * 528;
  const int r_rd = lane >> 2;            // bf16 readback row 0..15
  const int c_rd = (lane & 3) * 16;      // bf16 readback col (32B/lane)
  const int fr_rd = lane >> 3;           // fp32 readback row 0..7
  const int fc_rd = (lane & 7) * 4;      // fp32 readback col (first 16B)

  for (int g = 0; g < total; g += 2) {
    const bool bigW = (g > 0) && ((g & (NK - 1)) == 0);  // first tile after epi
    run_ktile(0, g + 2, (g + 2 < total), true, bigW);
    run_ktile(1, g + 3, (g + 3 < total), false, false);
    if (((g + 2) & (NK - 1)) == 0) {
      // ---- epilogue: wave-local slab repack -> full-line NT stores.
      //      DS ops are in-order per wave; LGKM0 is wave-local (staging
      //      gload_lds counts in vmcnt, not lgkmcnt). ----
      const int m0 = (ms * TS + (g >> kshift)) * 256;
      if (RELU_BF16_OUT) {
        unsigned short* Cb = (unsigned short*)Cv + (size_t)e * cStrideE;
#pragma unroll
        for (int mi = 0; mi < 8; ++mi) {
#pragma unroll
          for (int ni = 0; ni < 4; ++ni)
#pragma unroll
            for (int r = 0; r < 4; ++r) {
              float v = acc[mi][ni][r];
              v = v > 0.f ? v : 0.f;
              slabW[(rq + r) * 66 + ni * 16 + cq] = f2bf(v);
            }
          LGKM0();
          u32x4 w0 = *(const u32x4*)&slabW[r_rd * 66 + c_rd];
          u32x4 w1 = *(const u32x4*)&slabW[r_rd * 66 + c_rd + 8];
          unsigned short* dst =
              Cb + (size_t)(m0 + wm * 128 + mi * 16 + r_rd) * N + n0 + wn * 64 + c_rd;
          __builtin_nontemporal_store(w0, (u32x4*)dst);
          __builtin_nontemporal_store(w1, (u32x4*)(dst + 8));
        }
        CFENCE();   // 16 NT stores in flight -> next K-tile ends with VM24
      } else {
        float* Cf = (float*)Cv + (size_t)e * cStrideE;
#pragma unroll
        for (int mi = 0; mi < 8; ++mi) {
#pragma unroll
          for (int hr = 0; hr < 2; ++hr) {
            if ((rq >> 3) == hr) {
#pragma unroll
              for (int ni = 0; ni < 4; ++ni)
#pragma unroll
                for (int r = 0; r < 4; ++r)
                  slabF[((rq & 7) + r) * 66 + ni * 16 + cq] = acc[mi][ni][r];
            }
            LGKM0();
            f32x4 w0 = *(const f32x4*)&slabF[fr_rd * 66 + fc_rd];
            f32x4 w1 = *(const f32x4*)&slabF[fr_rd * 66 + 32 + fc_rd];
            float* dst =
                Cf + (size_t)(m0 + wm * 128 + mi * 16 + hr * 8 + fr_rd) * N + n0 + wn * 64;
            __builtin_nontemporal_store(w0, (f32x4*)(dst + fc_rd));
            __builtin_nontemporal_store(w1, (f32x4*)(dst + 32 + fc_rd));
          }
        }
        CFENCE();   // 32 NT stores in flight -> next K-tile ends with VM40
      }
#pragma unroll
      for (int mi = 0; mi < 8; ++mi)
#pragma unroll
        for (int ni = 0; ni < 4; ++ni)
          acc[mi][ni] = (f32x4){0.f, 0.f, 0.f, 0.f};
    }
  }
}

// Zero-workspace fp32 fallback (correct, slow). One block per token row.
__global__ __launch_bounds__(256)
void fused_naive(const float* __restrict__ x, const float* __restrict__ wi,
                 const float* __restrict__ wo, float* __restrict__ out) {
  __shared__ float xs[D_N];
  __shared__ float hs[F_N];
  const size_t row = blockIdx.x;
  const int e = (int)(row / (W_N * C_N));
  const float* xr = x + row * D_N;
  const float* wie = wi + (size_t)e * D_N * F_N;
  const float* woe = wo + (size_t)e * F_N * D_N;
  const int t = threadIdx.x;
  for (int d = t; d < D_N; d += 256) xs[d] = xr[d];
  __syncthreads();
  for (int f = t; f < F_N; f += 256) {
    float a = 0.f;
    for (int d = 0; d < D_N; ++d) a += xs[d] * wie[(size_t)d * F_N + f];
    hs[f] = a > 0.f ? a : 0.f;
  }
  __syncthreads();
  float* orow = out + row * D_N;
  for (int d = t; d < D_N; d += 256) {
    float a = 0.f;
    for (int f = 0; f < F_N; ++f) a += hs[f] * woe[(size_t)f * D_N + d];
    orow[d] = a;
  }
}

extern "C" void kernel_launch(void* const* d_in, const int* in_sizes, int n_in,
                              void* d_out, int out_size, void* d_ws, size_t ws_size,
                              hipStream_t stream) {
  const float* x  = (const float*)d_in[0];
  // d_in[1] = experts_capacity_usage: unused by the reference math
  const float* wi = (const float*)d_in[2];
  const float* wo = (const float*)d_in[3];
  float* out = (float*)d_out;

  const size_t WT   = (size_t)E_N * D_N * F_N;       // elems per weight tensor
  unsigned short* wiT = (unsigned short*)d_ws;       // [E][F][D] bf16
  unsigned short* woT = wiT + WT;                    // [E][D][F] bf16
  unsigned short* P   = woT + WT;
  const size_t baseB = 2 * WT * 2;                   // 32 MiB
  const size_t XB_B  = (size_t)E_N * ME * D_N * 2;   // x as bf16
  const size_t HF_B  = (size_t)E_N * ME * F_N * 2;   // full h

  const dim3 blk(256);
  if (ws_size >= baseB + XB_B + HF_B) {
    // 128 KiB staging + 16.5 KiB wave-local repack slabs = 147968 B
    hipFuncSetAttribute(reinterpret_cast<const void*>(gemm256p<true>),
                        hipFuncAttributeMaxDynamicSharedMemorySize, 147968);
    hipFuncSetAttribute(reinterpret_cast<const void*>(gemm256p<false>),
                        hipFuncAttributeMaxDynamicSharedMemorySize, 147968);
    unsigned short* xb = P;
    unsigned short* h  = P + XB_B / 2;
    prep_fused<<<dim3(6144), blk, 0, stream>>>(x, wi, wo, xb, wiT, woT);
    // GEMM1: per expert M=8192,N=2048,K=512 -> nT=8, TS=8 row-tiles/block
    gemm256p<true><<<dim3(256), dim3(512), 147968, stream>>>(
        xb, wiT, h, F_N, D_N, F_N / 256,
        (size_t)ME * D_N, (size_t)F_N * D_N, (size_t)ME * F_N);
    // GEMM2: per expert M=8192,N=512,K=2048 -> nT=2, TS=2 row-tiles/block
    gemm256p<false><<<dim3(256), dim3(512), 147968, stream>>>(
        h, woT, out, D_N, F_N, D_N / 256,
        (size_t)ME * F_N, (size_t)D_N * F_N, (size_t)ME * D_N);
  } else {
    fused_naive<<<dim3(E_N * W_N * C_N), blk, 0, stream>>>(x, wi, wo, out);
  }
}